// Round 27
// baseline (196.597 us; speedup 1.0000x reference)
//
#include <hip/hip_runtime.h>
#include <hip/hip_bf16.h>
#include <stdint.h>

// Problem constants
#define EDIM 1024
#define NH   16
#define HD   64
#define BB   4
#define SS   2048
#define MROWS (BB*SS)   // 8192

typedef __bf16 bf16x8 __attribute__((ext_vector_type(8)));
typedef __bf16 bf16x4 __attribute__((ext_vector_type(4)));
typedef float  f32x4  __attribute__((ext_vector_type(4)));
typedef float  f32x16 __attribute__((ext_vector_type(16)));
typedef int    int2v  __attribute__((ext_vector_type(2)));

__device__ __forceinline__ void async16(const void* g, void* lds) {
    __builtin_amdgcn_global_load_lds((__attribute__((address_space(1))) void*)(g),
                                     (__attribute__((address_space(3))) void*)(lds),
                                     16, 0, 0);
}

__device__ __forceinline__ f32x4 mfma16(bf16x8 a, bf16x8 b, f32x4 c) {
    return __builtin_amdgcn_mfma_f32_16x16x32_bf16(a, b, c, 0, 0, 0);
}
__device__ __forceinline__ f32x16 mfma32(bf16x8 a, bf16x8 b, f32x16 c) {
    return __builtin_amdgcn_mfma_f32_32x32x16_bf16(a, b, c, 0, 0, 0);
}

// pack two f32 -> one u32 of 2 bf16 (compiler emits v_cvt_pk_bf16_f32)
__device__ __forceinline__ int pkbf16(float a, float b) {
    union { __bf16 h[2]; int i; } u;
    u.h[0] = (__bf16)a; u.h[1] = (__bf16)b;
    return u.i;
}

// ---------------- fp32 -> bf16 conversion (vectorized) ----------------
__global__ __launch_bounds__(256) void cvt_kernel(const float* __restrict__ s,
                                                  __bf16* __restrict__ d, int n) {
    int i = (blockIdx.x * 256 + threadIdx.x) * 4;
    if (i < n) {
        float4 v = *reinterpret_cast<const float4*>(s + i);
        bf16x4 o;
        o.x = (__bf16)v.x; o.y = (__bf16)v.y; o.z = (__bf16)v.z; o.w = (__bf16)v.w;
        *reinterpret_cast<bf16x4*>(d + i) = o;
    }
}

// fused conversion of the 4 weight matrices (dest contiguous: wq|wk|wv|wo)
__global__ __launch_bounds__(256) void cvt4_kernel(const float* __restrict__ s0,
                                                   const float* __restrict__ s1,
                                                   const float* __restrict__ s2,
                                                   const float* __restrict__ s3,
                                                   __bf16* __restrict__ d) {
    int m = blockIdx.x >> 10;                     // 1024 blocks per matrix
    const float* s = (m == 0) ? s0 : (m == 1) ? s1 : (m == 2) ? s2 : s3;
    int i = ((blockIdx.x & 1023) * 256 + threadIdx.x) * 4;
    float4 v = *reinterpret_cast<const float4*>(s + i);
    bf16x4 o;
    o.x = (__bf16)v.x; o.y = (__bf16)v.y; o.z = (__bf16)v.z; o.w = (__bf16)v.w;
    *reinterpret_cast<bf16x4*>(d + (size_t)m * (EDIM * EDIM) + i) = o;
}

// ---- shared GEMM helpers: 128x128 tile, BK=64, dbuf, 8-slot XOR swizzle ----
// LDS tile: 128 rows x 128 B (64 bf16). Physical slot = logical_slot ^ (row&7).
struct GCtx { const __bf16 *ap, *bp; };

__device__ __forceinline__ void g_stage(GCtx& c, char* As, char* Bs, int wb) {
    #pragma unroll
    for (int i = 0; i < 4; ++i) {
        async16(c.ap + i * 32 * EDIM, As + wb + i * 4096);
        async16(c.bp + i * 32 * EDIM, Bs + wb + i * 4096);
    }
    c.ap += 64; c.bp += 64;
}

__device__ __forceinline__ void g_compute(const char* As, const char* Bs,
                                          int wm, int wn, int lrow, int lslot,
                                          f32x4 acc[4][4]) {
    #pragma unroll
    for (int kc = 0; kc < 2; ++kc) {
        bf16x8 af[4], bfr[4];
        #pragma unroll
        for (int mf = 0; mf < 4; ++mf) {
            int row = wm + mf * 16 + lrow;
            af[mf] = *reinterpret_cast<const bf16x8*>(
                As + row * 128 + (((kc * 4 + lslot) ^ (row & 7)) << 4));
        }
        #pragma unroll
        for (int nf = 0; nf < 4; ++nf) {
            int row = wn + nf * 16 + lrow;
            bfr[nf] = *reinterpret_cast<const bf16x8*>(
                Bs + row * 128 + (((kc * 4 + lslot) ^ (row & 7)) << 4));
        }
        __builtin_amdgcn_s_setprio(1);
        #pragma unroll
        for (int mf = 0; mf < 4; ++mf)
            #pragma unroll
            for (int nf = 0; nf < 4; ++nf)
                acc[mf][nf] = mfma16(af[mf], bfr[nf], acc[mf][nf]);
        __builtin_amdgcn_s_setprio(0);
    }
}

#define GEMM_DBUF_LOOP()                                                      \
    g_stage(ctx, As0, Bs0, wb);                                               \
    for (int kt = 0; kt < 16; kt += 2) {                                      \
        g_stage(ctx, As1, Bs1, wb);                                           \
        asm volatile("s_waitcnt vmcnt(8)" ::: "memory");                      \
        __builtin_amdgcn_s_barrier();                                         \
        __builtin_amdgcn_sched_barrier(0);                                    \
        g_compute(As0, Bs0, wm, wn, lrow, lslot, acc);                        \
        __builtin_amdgcn_sched_barrier(0);                                    \
        __builtin_amdgcn_s_barrier();                                         \
        if (kt + 2 < 16) {                                                    \
            g_stage(ctx, As0, Bs0, wb);                                       \
            asm volatile("s_waitcnt vmcnt(8)" ::: "memory");                  \
        } else {                                                              \
            asm volatile("s_waitcnt vmcnt(0)" ::: "memory");                  \
        }                                                                     \
        __builtin_amdgcn_s_barrier();                                         \
        __builtin_amdgcn_sched_barrier(0);                                    \
        g_compute(As1, Bs1, wm, wn, lrow, lslot, acc);                        \
        __builtin_amdgcn_sched_barrier(0);                                    \
        __builtin_amdgcn_s_barrier();                                         \
    }

// XCD-aware block remap (T1): neutral-measured (R26), kept as harmless.
#define GEMM_PREAMBLE(Aptr, Wptr)                                             \
    const int tid = threadIdx.x;                                              \
    const int w = tid >> 6, l = tid & 63;                                     \
    const int _b = blockIdx.y * 64 + blockIdx.x;                              \
    const int _g = _b & 7, _i = _b >> 3;                                      \
    const int bm = (_g * 8 + (_i & 7)) * 128, bn = (_i >> 3) * 128;           \
    const int wm = (w >> 1) * 64, wn = (w & 1) * 64;                          \
    f32x4 acc[4][4] = {};                                                     \
    const int lrow = l & 15;                                                  \
    const int lslot = l >> 4;                                                 \
    const int row0 = tid >> 3;                                                \
    const int gs = ((tid & 7) ^ (row0 & 7)) << 3;                             \
    const int wb = w * 1024;                                                  \
    GCtx ctx;                                                                 \
    ctx.ap = (Aptr) + (size_t)(bm + row0) * EDIM + gs;                        \
    ctx.bp = (Wptr) + (size_t)(bn + row0) * EDIM + gs;

// ---------------- Fused QKV GEMM: N=3072 (W rows 0..1023=Q, ..2047=K, ..3071=V) --
__global__ __launch_bounds__(256) void gemm_qkv(const __bf16* __restrict__ A,
                                                const __bf16* __restrict__ W,
                                                const float* __restrict__ bq,
                                                const float* __restrict__ bk,
                                                const float* __restrict__ bv,
                                                __bf16* __restrict__ Qb,
                                                __bf16* __restrict__ Kb,
                                                __bf16* __restrict__ Vtb) {
    __shared__ char As0[128 * 128], Bs0[128 * 128];
    __shared__ char As1[128 * 128], Bs1[128 * 128];
    GEMM_PREAMBLE(A, W)
    GEMM_DBUF_LOOP()

    const int mat = bn >> 10;                       // 0=Q, 1=K, 2=V (block-uniform)
    const float* bias = (mat == 0) ? bq : (mat == 1) ? bk : bv;

    if (mat == 2) {
        // V^T: packed bf16x4 along s (r=0..3 consecutive), coalesced-ish 8B stores
        #pragma unroll
        for (int nf = 0; nf < 4; ++nf) {
            int nn = (bn + wn + nf * 16 + lrow) & 1023;
            int h = nn >> 6, d = nn & 63;
            float bval = bias[nn];
            #pragma unroll
            for (int mf = 0; mf < 4; ++mf) {
                int mg0 = bm + wm + mf * 16 + (l >> 4) * 4;
                int b = mg0 >> 11, s = mg0 & 2047;
                bf16x4 o4;
                o4.x = (__bf16)(acc[mf][nf][0] + bval);
                o4.y = (__bf16)(acc[mf][nf][1] + bval);
                o4.z = (__bf16)(acc[mf][nf][2] + bval);
                o4.w = (__bf16)(acc[mf][nf][3] + bval);
                *reinterpret_cast<bf16x4*>(
                    Vtb + ((size_t)(b * NH + h) * HD + d) * SS + s) = o4;
            }
        }
    } else {
        __bf16* qk = (mat == 0) ? Qb : Kb;
        #pragma unroll
        for (int nf = 0; nf < 4; ++nf) {
            int nn = (bn + wn + nf * 16 + lrow) & 1023;
            int h = nn >> 6, d = nn & 63;
            float bval = bias[nn];
            #pragma unroll
            for (int mf = 0; mf < 4; ++mf) {
                #pragma unroll
                for (int r = 0; r < 4; ++r) {
                    int mg = bm + wm + mf * 16 + (l >> 4) * 4 + r;
                    int b = mg >> 11, s = mg & 2047;
                    qk[((size_t)(b * NH + h) * SS + s) * HD + d] =
                        (__bf16)(acc[mf][nf][r] + bval);
                }
            }
        }
    }
}

// ---------------- Output GEMM: fp32 out ----------------
__global__ __launch_bounds__(256) void gemm_out(const __bf16* __restrict__ A,
                                                const __bf16* __restrict__ W,
                                                const float* __restrict__ bias,
                                                float* __restrict__ dst) {
    __shared__ char As0[128 * 128], Bs0[128 * 128];
    __shared__ char As1[128 * 128], Bs1[128 * 128];
    GEMM_PREAMBLE(A, W)
    GEMM_DBUF_LOOP()

    #pragma unroll
    for (int nf = 0; nf < 4; ++nf) {
        int ng = bn + wn + nf * 16 + lrow;
        float bval = bias[ng];
        #pragma unroll
        for (int mf = 0; mf < 4; ++mf) {
            #pragma unroll
            for (int r = 0; r < 4; ++r) {
                int mg = bm + wm + mf * 16 + (l >> 4) * 4 + r;
                dst[(size_t)mg * EDIM + ng] = acc[mf][nf][r] + bval;
            }
        }
    }
}

// ---------------- Flash attention pass 1 (causal, swapped-QK^T, split-KV) ----
// blockIdx.y decode: y<8 -> SPLIT qt = 7-(y>>1), half = y&1 (qt 4..7);
//                    y>=8 -> UNSPLIT qt = 11-y (qt 3..0).
#define SCL2E 0.18033688f   /* 0.125 * log2(e) */

__global__ __launch_bounds__(512) void attn_kernel(const __bf16* __restrict__ Q,
                                                   const __bf16* __restrict__ K,
                                                   const __bf16* __restrict__ Vt,
                                                   __bf16* __restrict__ Oa,
                                                   __bf16* __restrict__ Opart,
                                                   float2* __restrict__ Ml) {
    __shared__ char ks0[64 * 128], vs0[64 * 128];
    __shared__ char ks1[64 * 128], vs1[64 * 128];

    const int bh = blockIdx.x;          // 0..63
    const int y = blockIdx.y;           // 0..11
    const bool split = (y < 8);
    const int qt = split ? (7 - (y >> 1)) : (11 - y);
    const int half = split ? (y & 1) : 0;
    const int tid = threadIdx.x;
    const int w = tid >> 6;             // warp 0..7
    const int l = tid & 63;
    const int lo = l & 31;
    const int hi = l >> 5;

    const __bf16* Qp = Q + (size_t)bh * (SS * HD);
    const __bf16* Kp = K + (size_t)bh * (SS * HD);
    const __bf16* Vp = Vt + (size_t)bh * (HD * SS);

    // Q B-fragments: col=q=lo, k = d = kc*16 + hi*8 + j
    const int qg = qt * 256 + w * 32 + lo;
    bf16x8 qf[4];
    #pragma unroll
    for (int kc = 0; kc < 4; ++kc)
        qf[kc] = *reinterpret_cast<const bf16x8*>(Qp + (size_t)qg * HD + kc * 16 + hi * 8);

    // KV tile range for this block
    const int nt_all = 4 * qt + 4;
    const int tcount = split ? (nt_all >> 1) : nt_all;    // always even
    const int kt0 = split ? (half * tcount) : 0;

    // staging: one 16B chunk per thread per matrix
    const int rowS = tid >> 3, cbS = tid & 7;
    const int gsS = (cbS ^ (rowS & 7)) << 3;
    const int wb = w * 1024;
    const __bf16* kp = Kp + (size_t)(kt0 * 64 + rowS) * HD + gsS;
    const __bf16* vp = Vp + (size_t)rowS * SS + kt0 * 64 + gsS;

    f32x16 oacc[2] = {};                 // O^T[d][q = lo]
    float mrow = -1e30f;
    float lsum = 0.f;

    const int qwhi = qt * 256 + w * 32 + 31;

    auto compute = [&](const char* ksb, const char* vsb, int kv0) {
        f32x16 acc[2] = {};
        __builtin_amdgcn_s_setprio(1);
        #pragma unroll
        for (int tb = 0; tb < 2; ++tb) {
            const int t = tb * 32 + lo;
            const char* krow = ksb + t * 128;
            const int tx = (t & 7);
            #pragma unroll
            for (int kc = 0; kc < 4; ++kc) {
                bf16x8 kf = *reinterpret_cast<const bf16x8*>(krow + ((2 * kc + hi) ^ tx) * 16);
                acc[tb] = mfma32(kf, qf[kc], acc[tb]);
            }
        }
        __builtin_amdgcn_s_setprio(0);

        // causal mask near the diagonal (warp-uniform predicate)
        if (kv0 + 63 > qg - lo) {
            #pragma unroll
            for (int tb = 0; tb < 2; ++tb)
                #pragma unroll
                for (int r = 0; r < 16; ++r) {
                    int t = kv0 + tb * 32 + ((r & 3) + 8 * (r >> 2)) + 4 * hi;
                    if (t > qg) acc[tb][r] = -1e30f;
                }
        }

        // in-register online softmax; TREE max-reduce (depth ~6 vs 31 serial)
        float mx4[4];
        #pragma unroll
        for (int j = 0; j < 4; ++j) {
            float a = fmaxf(fmaxf(acc[0][j * 4 + 0], acc[0][j * 4 + 1]),
                            fmaxf(acc[0][j * 4 + 2], acc[0][j * 4 + 3]));
            float b = fmaxf(fmaxf(acc[1][j * 4 + 0], acc[1][j * 4 + 1]),
                            fmaxf(acc[1][j * 4 + 2], acc[1][j * 4 + 3]));
            mx4[j] = fmaxf(a, b);
        }
        float mx = fmaxf(fmaxf(mx4[0], mx4[1]), fmaxf(mx4[2], mx4[3]));
        mx = fmaxf(mx, __shfl_xor(mx, 32));
        float mxs = mx * SCL2E;
        if (!__all(mxs <= mrow + 8.0f)) {        // T13 defer-max
            float mnew = fmaxf(mrow, mxs);
            float alpha = exp2f(mrow - mnew);
            mrow = mnew;
            lsum *= alpha;
            oacc[0] *= alpha;
            oacc[1] *= alpha;
        }
        // 4-way partial sums: dependency chain 8 adds instead of 32
        float ps[4] = {0.f, 0.f, 0.f, 0.f};
        #pragma unroll
        for (int tb = 0; tb < 2; ++tb)
            #pragma unroll
            for (int r = 0; r < 16; ++r) {
                float p = exp2f(fmaf(acc[tb][r], SCL2E, -mrow));
                acc[tb][r] = p;
                ps[r & 3] += p;
            }
        lsum += (ps[0] + ps[1]) + (ps[2] + ps[3]);

        // P -> bf16 fragments via cvt_pk + permlane32_swap
        bf16x8 pa[4];
        #pragma unroll
        for (int ks2 = 0; ks2 < 4; ++ks2) {
            const int tb = ks2 >> 1, rb = (ks2 & 1) * 8;
            int a0 = pkbf16(acc[tb][rb + 0], acc[tb][rb + 1]);
            int b0 = pkbf16(acc[tb][rb + 4], acc[tb][rb + 5]);
            int a1 = pkbf16(acc[tb][rb + 2], acc[tb][rb + 3]);
            int b1 = pkbf16(acc[tb][rb + 6], acc[tb][rb + 7]);
            int2v s1 = __builtin_amdgcn_permlane32_swap(a0, b0, false, false);
            int2v s2 = __builtin_amdgcn_permlane32_swap(a1, b1, false, false);
            union { int i[4]; bf16x8 v; } u;
            u.i[0] = s1[0]; u.i[1] = s2[0]; u.i[2] = s1[1]; u.i[3] = s2[1];
            pa[ks2] = u.v;
        }

        // PV transposed: O^T[d][q] += V^T[d][t] * P^T[t][q]
        __builtin_amdgcn_s_setprio(1);
        #pragma unroll
        for (int ks2 = 0; ks2 < 4; ++ks2) {
            #pragma unroll
            for (int db = 0; db < 2; ++db) {
                const int d = db * 32 + lo;
                bf16x8 vb = *reinterpret_cast<const bf16x8*>(
                    vsb + d * 128 + (((2 * ks2 + hi) ^ (d & 7)) * 16));
                oacc[db] = mfma32(vb, pa[ks2], oacc[db]);
            }
        }
        __builtin_amdgcn_s_setprio(0);
    };

    // prologue: stage tile 0 into buffer 0
    async16(kp, ks0 + wb);
    async16(vp, vs0 + wb);
    kp += 64 * HD; vp += 64;

    for (int kt = 0; kt < tcount; kt += 2) {
        // ---- phase A: compute tile kt (buf0); prefetch kt+1 -> buf1
        async16(kp, ks1 + wb);
        async16(vp, vs1 + wb);
        kp += 64 * HD; vp += 64;
        asm volatile("s_waitcnt vmcnt(2)" ::: "memory");   // tile kt landed
        __builtin_amdgcn_s_barrier();
        __builtin_amdgcn_sched_barrier(0);
        if ((kt0 + kt) * 64 <= qwhi) compute(ks0, vs0, (kt0 + kt) * 64);
        __builtin_amdgcn_sched_barrier(0);
        __builtin_amdgcn_s_barrier();                      // buf0 reads done

        // ---- phase B: compute tile kt+1 (buf1); prefetch kt+2 -> buf0
        if (kt + 2 < tcount) {
            async16(kp, ks0 + wb);
            async16(vp, vs0 + wb);
            kp += 64 * HD; vp += 64;
            asm volatile("s_waitcnt vmcnt(2)" ::: "memory");
        } else {
            asm volatile("s_waitcnt vmcnt(0)" ::: "memory");
        }
        __builtin_amdgcn_s_barrier();
        __builtin_amdgcn_sched_barrier(0);
        if ((kt0 + kt + 1) * 64 <= qwhi) compute(ks1, vs1, (kt0 + kt + 1) * 64);
        __builtin_amdgcn_sched_barrier(0);
        __builtin_amdgcn_s_barrier();                      // buf1 reads done
    }

    // epilogue
    float lsumt = lsum + __shfl_xor(lsum, 32);   // halves hold partial sums over t
    if (split) {
        // unnormalized bf16 partial + (m, l); qp = qg - 1024 (qt >= 4)
        const int qp = qg - 1024;
        __bf16* prow = Opart + (((size_t)(half * 64 + bh) * 1024) + qp) * 64;
        #pragma unroll
        for (int db = 0; db < 2; ++db) {
            #pragma unroll
            for (int g = 0; g < 4; ++g) {
                int d0 = db * 32 + g * 8 + 4 * hi;
                bf16x4 o4;
                o4.x = (__bf16)oacc[db][g * 4 + 0];
                o4.y = (__bf16)oacc[db][g * 4 + 1];
                o4.z = (__bf16)oacc[db][g * 4 + 2];
                o4.w = (__bf16)oacc[db][g * 4 + 3];
                *reinterpret_cast<bf16x4*>(prow + d0) = o4;
            }
        }
        if (hi == 0)
            Ml[(size_t)(half * 64 + bh) * 1024 + qp] = make_float2(mrow, lsumt);
    } else {
        const int b = bh >> 4, h = bh & 15;
        float inv = 1.0f / lsumt;
        __bf16* orow = Oa + ((size_t)(b * SS + qg)) * EDIM + h * HD;
        #pragma unroll
        for (int db = 0; db < 2; ++db) {
            #pragma unroll
            for (int g = 0; g < 4; ++g) {
                int d0 = db * 32 + g * 8 + 4 * hi;
                bf16x4 o4;
                o4.x = (__bf16)(oacc[db][g * 4 + 0] * inv);
                o4.y = (__bf16)(oacc[db][g * 4 + 1] * inv);
                o4.z = (__bf16)(oacc[db][g * 4 + 2] * inv);
                o4.w = (__bf16)(oacc[db][g * 4 + 3] * inv);
                *reinterpret_cast<bf16x4*>(orow + d0) = o4;
            }
        }
    }
}

// ---------------- merge pass: combine split-KV partials for q >= 1024 ----------
__global__ __launch_bounds__(256) void merge_kernel(const __bf16* __restrict__ Opart,
                                                    const float2* __restrict__ Ml,
                                                    __bf16* __restrict__ Oa) {
    int t = blockIdx.x * 256 + threadIdx.x;   // 64 bh * 1024 qp * 8 d-octets
    int d8 = t & 7;
    int qp = (t >> 3) & 1023;
    int bh = t >> 13;
    size_t r0 = ((size_t)bh * 1024 + qp);
    size_t r1 = ((size_t)(64 + bh) * 1024 + qp);
    float2 ml0 = Ml[r0], ml1 = Ml[r1];
    float m = fmaxf(ml0.x, ml1.x);
    float a0 = exp2f(ml0.x - m), a1 = exp2f(ml1.x - m);
    float inv = 1.0f / (a0 * ml0.y + a1 * ml1.y);
    bf16x8 o0 = *reinterpret_cast<const bf16x8*>(Opart + r0 * 64 + d8 * 8);
    bf16x8 o1 = *reinterpret_cast<const bf16x8*>(Opart + r1 * 64 + d8 * 8);
    bf16x8 r;
    #pragma unroll
    for (int j = 0; j < 8; ++j)
        r[j] = (__bf16)((a0 * (float)o0[j] + a1 * (float)o1[j]) * inv);
    int b = bh >> 4, h = bh & 15, q = 1024 + qp;
    *reinterpret_cast<bf16x8*>(Oa + ((size_t)(b * SS + q)) * EDIM + h * HD + d8 * 8) = r;
}

// ---------------- launch ----------------
extern "C" void kernel_launch(void* const* d_in, const int* in_sizes, int n_in,
                              void* d_out, int out_size, void* d_ws, size_t ws_size,
                              hipStream_t stream) {
    const float* x  = (const float*)d_in[0];
    const float* Wq = (const float*)d_in[1];
    const float* bq = (const float*)d_in[2];
    const float* Wk = (const float*)d_in[3];
    const float* bk = (const float*)d_in[4];
    const float* Wv = (const float*)d_in[5];
    const float* bv = (const float*)d_in[6];
    const float* Wo = (const float*)d_in[7];
    const float* bo = (const float*)d_in[8];

    char* ws = (char*)d_ws;
    const size_t SZ_XB  = (size_t)MROWS * EDIM * 2;       // 16 MB
    const size_t SZ_W   = (size_t)EDIM * EDIM * 2;        // 2 MB
    const size_t SZ_QKV = (size_t)BB * NH * SS * HD * 2;  // 16 MB

    __bf16* xb  = (__bf16*)(ws);
    __bf16* wqb = (__bf16*)(ws + SZ_XB);                  // wq|wk|wv|wo contiguous
    __bf16* wob = (__bf16*)(ws + SZ_XB + 3 * SZ_W);
    __bf16* Qb  = (__bf16*)(ws + SZ_XB + 4 * SZ_W);
    __bf16* Kb  = (__bf16*)(ws + SZ_XB + 4 * SZ_W + SZ_QKV);
    __bf16* Vtb = (__bf16*)(ws + SZ_XB + 4 * SZ_W + 2 * SZ_QKV);
    __bf16* Oab = (__bf16*)(ws + SZ_XB + 4 * SZ_W + 3 * SZ_QKV);
    // split-KV scratch (reuses regions dead after gemm_qkv):
    __bf16* Opart = (__bf16*)(ws);                        // xb region, exactly 16 MB
    float2* Mlb   = (float2*)(ws + SZ_XB);                // wq region (dead), 1 MB

    cvt_kernel<<<MROWS * EDIM / 1024, 256, 0, stream>>>(x, xb, MROWS * EDIM);
    cvt4_kernel<<<4096, 256, 0, stream>>>(Wq, Wk, Wv, Wo, wqb);

    // fused QKV projection: N = 3072
    gemm_qkv<<<dim3(MROWS / 128, 3 * EDIM / 128), 256, 0, stream>>>(
        xb, wqb, bq, bk, bv, Qb, Kb, Vtb);

    attn_kernel<<<dim3(BB * NH, 12), 512, 0, stream>>>(Qb, Kb, Vtb, Oab, Opart, Mlb);
    merge_kernel<<<64 * 1024 * 8 / 256, 256, 0, stream>>>(Opart, Mlb, Oab);

    gemm_out<<<dim3(MROWS / 128, EDIM / 128), 256, 0, stream>>>(
        Oab, wob, bo, (float*)d_out);
}

// Round 28
// 176.230 us; speedup vs baseline: 1.1156x; 1.1156x over previous
//
#include <hip/hip_runtime.h>
#include <hip/hip_bf16.h>
#include <stdint.h>

// Problem constants
#define EDIM 1024
#define NH   16
#define HD   64
#define BB   4
#define SS   2048
#define MROWS (BB*SS)   // 8192

typedef __bf16 bf16x8 __attribute__((ext_vector_type(8)));
typedef __bf16 bf16x4 __attribute__((ext_vector_type(4)));
typedef float  f32x4  __attribute__((ext_vector_type(4)));
typedef float  f32x16 __attribute__((ext_vector_type(16)));
typedef int    int2v  __attribute__((ext_vector_type(2)));

__device__ __forceinline__ void async16(const void* g, void* lds) {
    __builtin_amdgcn_global_load_lds((__attribute__((address_space(1))) void*)(g),
                                     (__attribute__((address_space(3))) void*)(lds),
                                     16, 0, 0);
}

__device__ __forceinline__ f32x4 mfma16(bf16x8 a, bf16x8 b, f32x4 c) {
    return __builtin_amdgcn_mfma_f32_16x16x32_bf16(a, b, c, 0, 0, 0);
}
__device__ __forceinline__ f32x16 mfma32(bf16x8 a, bf16x8 b, f32x16 c) {
    return __builtin_amdgcn_mfma_f32_32x32x16_bf16(a, b, c, 0, 0, 0);
}

// pack two f32 -> one u32 of 2 bf16 (compiler emits v_cvt_pk_bf16_f32)
__device__ __forceinline__ int pkbf16(float a, float b) {
    union { __bf16 h[2]; int i; } u;
    u.h[0] = (__bf16)a; u.h[1] = (__bf16)b;
    return u.i;
}

// ---------------- fp32 -> bf16 conversion (vectorized) ----------------
__global__ __launch_bounds__(256) void cvt_kernel(const float* __restrict__ s,
                                                  __bf16* __restrict__ d, int n) {
    int i = (blockIdx.x * 256 + threadIdx.x) * 4;
    if (i < n) {
        float4 v = *reinterpret_cast<const float4*>(s + i);
        bf16x4 o;
        o.x = (__bf16)v.x; o.y = (__bf16)v.y; o.z = (__bf16)v.z; o.w = (__bf16)v.w;
        *reinterpret_cast<bf16x4*>(d + i) = o;
    }
}

// fused conversion of the 4 weight matrices (dest contiguous: wq|wk|wv|wo)
__global__ __launch_bounds__(256) void cvt4_kernel(const float* __restrict__ s0,
                                                   const float* __restrict__ s1,
                                                   const float* __restrict__ s2,
                                                   const float* __restrict__ s3,
                                                   __bf16* __restrict__ d) {
    int m = blockIdx.x >> 10;                     // 1024 blocks per matrix
    const float* s = (m == 0) ? s0 : (m == 1) ? s1 : (m == 2) ? s2 : s3;
    int i = ((blockIdx.x & 1023) * 256 + threadIdx.x) * 4;
    float4 v = *reinterpret_cast<const float4*>(s + i);
    bf16x4 o;
    o.x = (__bf16)v.x; o.y = (__bf16)v.y; o.z = (__bf16)v.z; o.w = (__bf16)v.w;
    *reinterpret_cast<bf16x4*>(d + (size_t)m * (EDIM * EDIM) + i) = o;
}

// ---- shared GEMM helpers: 128x128 tile, BK=64, dbuf, 8-slot XOR swizzle ----
// LDS tile: 128 rows x 128 B (64 bf16). Physical slot = logical_slot ^ (row&7).
struct GCtx { const __bf16 *ap, *bp; };

__device__ __forceinline__ void g_stage(GCtx& c, char* As, char* Bs, int wb) {
    #pragma unroll
    for (int i = 0; i < 4; ++i) {
        async16(c.ap + i * 32 * EDIM, As + wb + i * 4096);
        async16(c.bp + i * 32 * EDIM, Bs + wb + i * 4096);
    }
    c.ap += 64; c.bp += 64;
}

__device__ __forceinline__ void g_compute(const char* As, const char* Bs,
                                          int wm, int wn, int lrow, int lslot,
                                          f32x4 acc[4][4]) {
    #pragma unroll
    for (int kc = 0; kc < 2; ++kc) {
        bf16x8 af[4], bfr[4];
        #pragma unroll
        for (int mf = 0; mf < 4; ++mf) {
            int row = wm + mf * 16 + lrow;
            af[mf] = *reinterpret_cast<const bf16x8*>(
                As + row * 128 + (((kc * 4 + lslot) ^ (row & 7)) << 4));
        }
        #pragma unroll
        for (int nf = 0; nf < 4; ++nf) {
            int row = wn + nf * 16 + lrow;
            bfr[nf] = *reinterpret_cast<const bf16x8*>(
                Bs + row * 128 + (((kc * 4 + lslot) ^ (row & 7)) << 4));
        }
        __builtin_amdgcn_s_setprio(1);
        #pragma unroll
        for (int mf = 0; mf < 4; ++mf)
            #pragma unroll
            for (int nf = 0; nf < 4; ++nf)
                acc[mf][nf] = mfma16(af[mf], bfr[nf], acc[mf][nf]);
        __builtin_amdgcn_s_setprio(0);
    }
}

#define GEMM_DBUF_LOOP()                                                      \
    g_stage(ctx, As0, Bs0, wb);                                               \
    for (int kt = 0; kt < 16; kt += 2) {                                      \
        g_stage(ctx, As1, Bs1, wb);                                           \
        asm volatile("s_waitcnt vmcnt(8)" ::: "memory");                      \
        __builtin_amdgcn_s_barrier();                                         \
        __builtin_amdgcn_sched_barrier(0);                                    \
        g_compute(As0, Bs0, wm, wn, lrow, lslot, acc);                        \
        __builtin_amdgcn_sched_barrier(0);                                    \
        __builtin_amdgcn_s_barrier();                                         \
        if (kt + 2 < 16) {                                                    \
            g_stage(ctx, As0, Bs0, wb);                                       \
            asm volatile("s_waitcnt vmcnt(8)" ::: "memory");                  \
        } else {                                                              \
            asm volatile("s_waitcnt vmcnt(0)" ::: "memory");                  \
        }                                                                     \
        __builtin_amdgcn_s_barrier();                                         \
        __builtin_amdgcn_sched_barrier(0);                                    \
        g_compute(As1, Bs1, wm, wn, lrow, lslot, acc);                        \
        __builtin_amdgcn_sched_barrier(0);                                    \
        __builtin_amdgcn_s_barrier();                                         \
    }

// XCD-aware block remap (T1): neutral-measured (R26), kept as harmless.
#define GEMM_PREAMBLE(Aptr, Wptr)                                             \
    const int tid = threadIdx.x;                                              \
    const int w = tid >> 6, l = tid & 63;                                     \
    const int _b = blockIdx.y * 64 + blockIdx.x;                              \
    const int _g = _b & 7, _i = _b >> 3;                                      \
    const int bm = (_g * 8 + (_i & 7)) * 128, bn = (_i >> 3) * 128;           \
    const int wm = (w >> 1) * 64, wn = (w & 1) * 64;                          \
    f32x4 acc[4][4] = {};                                                     \
    const int lrow = l & 15;                                                  \
    const int lslot = l >> 4;                                                 \
    const int row0 = tid >> 3;                                                \
    const int gs = ((tid & 7) ^ (row0 & 7)) << 3;                             \
    const int wb = w * 1024;                                                  \
    GCtx ctx;                                                                 \
    ctx.ap = (Aptr) + (size_t)(bm + row0) * EDIM + gs;                        \
    ctx.bp = (Wptr) + (size_t)(bn + row0) * EDIM + gs;

// ---------------- Fused QKV GEMM: N=3072 (W rows 0..1023=Q, ..2047=K, ..3071=V) --
__global__ __launch_bounds__(256) void gemm_qkv(const __bf16* __restrict__ A,
                                                const __bf16* __restrict__ W,
                                                const float* __restrict__ bq,
                                                const float* __restrict__ bk,
                                                const float* __restrict__ bv,
                                                __bf16* __restrict__ Qb,
                                                __bf16* __restrict__ Kb,
                                                __bf16* __restrict__ Vtb) {
    __shared__ char As0[128 * 128], Bs0[128 * 128];
    __shared__ char As1[128 * 128], Bs1[128 * 128];
    GEMM_PREAMBLE(A, W)
    GEMM_DBUF_LOOP()

    const int mat = bn >> 10;                       // 0=Q, 1=K, 2=V (block-uniform)
    const float* bias = (mat == 0) ? bq : (mat == 1) ? bk : bv;

    if (mat == 2) {
        // V^T: packed bf16x4 along s (r=0..3 consecutive), coalesced-ish 8B stores
        #pragma unroll
        for (int nf = 0; nf < 4; ++nf) {
            int nn = (bn + wn + nf * 16 + lrow) & 1023;
            int h = nn >> 6, d = nn & 63;
            float bval = bias[nn];
            #pragma unroll
            for (int mf = 0; mf < 4; ++mf) {
                int mg0 = bm + wm + mf * 16 + (l >> 4) * 4;
                int b = mg0 >> 11, s = mg0 & 2047;
                bf16x4 o4;
                o4.x = (__bf16)(acc[mf][nf][0] + bval);
                o4.y = (__bf16)(acc[mf][nf][1] + bval);
                o4.z = (__bf16)(acc[mf][nf][2] + bval);
                o4.w = (__bf16)(acc[mf][nf][3] + bval);
                *reinterpret_cast<bf16x4*>(
                    Vtb + ((size_t)(b * NH + h) * HD + d) * SS + s) = o4;
            }
        }
    } else {
        __bf16* qk = (mat == 0) ? Qb : Kb;
        #pragma unroll
        for (int nf = 0; nf < 4; ++nf) {
            int nn = (bn + wn + nf * 16 + lrow) & 1023;
            int h = nn >> 6, d = nn & 63;
            float bval = bias[nn];
            #pragma unroll
            for (int mf = 0; mf < 4; ++mf) {
                #pragma unroll
                for (int r = 0; r < 4; ++r) {
                    int mg = bm + wm + mf * 16 + (l >> 4) * 4 + r;
                    int b = mg >> 11, s = mg & 2047;
                    qk[((size_t)(b * NH + h) * SS + s) * HD + d] =
                        (__bf16)(acc[mf][nf][r] + bval);
                }
            }
        }
    }
}

// ---------------- Output GEMM: fp32 out ----------------
__global__ __launch_bounds__(256) void gemm_out(const __bf16* __restrict__ A,
                                                const __bf16* __restrict__ W,
                                                const float* __restrict__ bias,
                                                float* __restrict__ dst) {
    __shared__ char As0[128 * 128], Bs0[128 * 128];
    __shared__ char As1[128 * 128], Bs1[128 * 128];
    GEMM_PREAMBLE(A, W)
    GEMM_DBUF_LOOP()

    #pragma unroll
    for (int nf = 0; nf < 4; ++nf) {
        int ng = bn + wn + nf * 16 + lrow;
        float bval = bias[ng];
        #pragma unroll
        for (int mf = 0; mf < 4; ++mf) {
            #pragma unroll
            for (int r = 0; r < 4; ++r) {
                int mg = bm + wm + mf * 16 + (l >> 4) * 4 + r;
                dst[(size_t)mg * EDIM + ng] = acc[mf][nf][r] + bval;
            }
        }
    }
}

// ---------------- Flash attention pass 1 (causal, swapped-QK^T, split-KV) ----
// blockIdx.y decode: y<8 -> SPLIT qt = 7-(y>>1), half = y&1 (qt 4..7);
//                    y>=8 -> UNSPLIT qt = 11-y (qt 3..0).
#define SCL2E 0.18033688f   /* 0.125 * log2(e) */

__global__ __launch_bounds__(512) void attn_kernel(const __bf16* __restrict__ Q,
                                                   const __bf16* __restrict__ K,
                                                   const __bf16* __restrict__ Vt,
                                                   __bf16* __restrict__ Oa,
                                                   __bf16* __restrict__ Opart,
                                                   float2* __restrict__ Ml) {
    __shared__ char ks0[64 * 128], vs0[64 * 128];
    __shared__ char ks1[64 * 128], vs1[64 * 128];

    const int bh = blockIdx.x;          // 0..63
    const int y = blockIdx.y;           // 0..11
    const bool split = (y < 8);
    const int qt = split ? (7 - (y >> 1)) : (11 - y);
    const int half = split ? (y & 1) : 0;
    const int tid = threadIdx.x;
    const int w = tid >> 6;             // warp 0..7
    const int l = tid & 63;
    const int lo = l & 31;
    const int hi = l >> 5;

    const __bf16* Qp = Q + (size_t)bh * (SS * HD);
    const __bf16* Kp = K + (size_t)bh * (SS * HD);
    const __bf16* Vp = Vt + (size_t)bh * (HD * SS);

    // Q B-fragments: col=q=lo, k = d = kc*16 + hi*8 + j
    const int qg = qt * 256 + w * 32 + lo;
    bf16x8 qf[4];
    #pragma unroll
    for (int kc = 0; kc < 4; ++kc)
        qf[kc] = *reinterpret_cast<const bf16x8*>(Qp + (size_t)qg * HD + kc * 16 + hi * 8);

    // KV tile range for this block
    const int nt_all = 4 * qt + 4;
    const int tcount = split ? (nt_all >> 1) : nt_all;    // always even
    const int kt0 = split ? (half * tcount) : 0;

    // staging: one 16B chunk per thread per matrix
    const int rowS = tid >> 3, cbS = tid & 7;
    const int gsS = (cbS ^ (rowS & 7)) << 3;
    const int wb = w * 1024;
    const __bf16* kp = Kp + (size_t)(kt0 * 64 + rowS) * HD + gsS;
    const __bf16* vp = Vp + (size_t)rowS * SS + kt0 * 64 + gsS;

    f32x16 oacc[2] = {};                 // O^T[d][q = lo]
    float mrow = -1e30f;
    float lsum = 0.f;

    const int qwhi = qt * 256 + w * 32 + 31;

    auto compute = [&](const char* ksb, const char* vsb, int kv0) {
        f32x16 acc[2] = {};
        __builtin_amdgcn_s_setprio(1);
        #pragma unroll
        for (int tb = 0; tb < 2; ++tb) {
            const int t = tb * 32 + lo;
            const char* krow = ksb + t * 128;
            const int tx = (t & 7);
            #pragma unroll
            for (int kc = 0; kc < 4; ++kc) {
                bf16x8 kf = *reinterpret_cast<const bf16x8*>(krow + ((2 * kc + hi) ^ tx) * 16);
                acc[tb] = mfma32(kf, qf[kc], acc[tb]);
            }
        }
        __builtin_amdgcn_s_setprio(0);

        // causal mask near the diagonal (warp-uniform predicate)
        if (kv0 + 63 > qg - lo) {
            #pragma unroll
            for (int tb = 0; tb < 2; ++tb)
                #pragma unroll
                for (int r = 0; r < 16; ++r) {
                    int t = kv0 + tb * 32 + ((r & 3) + 8 * (r >> 2)) + 4 * hi;
                    if (t > qg) acc[tb][r] = -1e30f;
                }
        }

        // in-register online softmax (scalar m/lsum per lane; row = q = lo)
        float mx = acc[0][0];
        #pragma unroll
        for (int r = 1; r < 16; ++r) mx = fmaxf(mx, acc[0][r]);
        #pragma unroll
        for (int r = 0; r < 16; ++r) mx = fmaxf(mx, acc[1][r]);
        mx = fmaxf(mx, __shfl_xor(mx, 32));
        float mxs = mx * SCL2E;
        if (!__all(mxs <= mrow + 8.0f)) {        // T13 defer-max
            float mnew = fmaxf(mrow, mxs);
            float alpha = exp2f(mrow - mnew);
            mrow = mnew;
            lsum *= alpha;
            oacc[0] *= alpha;
            oacc[1] *= alpha;
        }
        float psum = 0.f;
        #pragma unroll
        for (int tb = 0; tb < 2; ++tb)
            #pragma unroll
            for (int r = 0; r < 16; ++r) {
                float p = exp2f(fmaf(acc[tb][r], SCL2E, -mrow));
                acc[tb][r] = p;
                psum += p;
            }
        lsum += psum;

        // P -> bf16 fragments via cvt_pk + permlane32_swap
        bf16x8 pa[4];
        #pragma unroll
        for (int ks2 = 0; ks2 < 4; ++ks2) {
            const int tb = ks2 >> 1, rb = (ks2 & 1) * 8;
            int a0 = pkbf16(acc[tb][rb + 0], acc[tb][rb + 1]);
            int b0 = pkbf16(acc[tb][rb + 4], acc[tb][rb + 5]);
            int a1 = pkbf16(acc[tb][rb + 2], acc[tb][rb + 3]);
            int b1 = pkbf16(acc[tb][rb + 6], acc[tb][rb + 7]);
            int2v s1 = __builtin_amdgcn_permlane32_swap(a0, b0, false, false);
            int2v s2 = __builtin_amdgcn_permlane32_swap(a1, b1, false, false);
            union { int i[4]; bf16x8 v; } u;
            u.i[0] = s1[0]; u.i[1] = s2[0]; u.i[2] = s1[1]; u.i[3] = s2[1];
            pa[ks2] = u.v;
        }

        // PV transposed: O^T[d][q] += V^T[d][t] * P^T[t][q]
        __builtin_amdgcn_s_setprio(1);
        #pragma unroll
        for (int ks2 = 0; ks2 < 4; ++ks2) {
            #pragma unroll
            for (int db = 0; db < 2; ++db) {
                const int d = db * 32 + lo;
                bf16x8 vb = *reinterpret_cast<const bf16x8*>(
                    vsb + d * 128 + (((2 * ks2 + hi) ^ (d & 7)) * 16));
                oacc[db] = mfma32(vb, pa[ks2], oacc[db]);
            }
        }
        __builtin_amdgcn_s_setprio(0);
    };

    // prologue: stage tile 0 into buffer 0
    async16(kp, ks0 + wb);
    async16(vp, vs0 + wb);
    kp += 64 * HD; vp += 64;

    for (int kt = 0; kt < tcount; kt += 2) {
        // ---- phase A: compute tile kt (buf0); prefetch kt+1 -> buf1
        async16(kp, ks1 + wb);
        async16(vp, vs1 + wb);
        kp += 64 * HD; vp += 64;
        asm volatile("s_waitcnt vmcnt(2)" ::: "memory");   // tile kt landed
        __builtin_amdgcn_s_barrier();
        __builtin_amdgcn_sched_barrier(0);
        if ((kt0 + kt) * 64 <= qwhi) compute(ks0, vs0, (kt0 + kt) * 64);
        __builtin_amdgcn_sched_barrier(0);
        __builtin_amdgcn_s_barrier();                      // buf0 reads done

        // ---- phase B: compute tile kt+1 (buf1); prefetch kt+2 -> buf0
        if (kt + 2 < tcount) {
            async16(kp, ks0 + wb);
            async16(vp, vs0 + wb);
            kp += 64 * HD; vp += 64;
            asm volatile("s_waitcnt vmcnt(2)" ::: "memory");
        } else {
            asm volatile("s_waitcnt vmcnt(0)" ::: "memory");
        }
        __builtin_amdgcn_s_barrier();
        __builtin_amdgcn_sched_barrier(0);
        if ((kt0 + kt + 1) * 64 <= qwhi) compute(ks1, vs1, (kt0 + kt + 1) * 64);
        __builtin_amdgcn_sched_barrier(0);
        __builtin_amdgcn_s_barrier();                      // buf1 reads done
    }

    // epilogue
    float lsumt = lsum + __shfl_xor(lsum, 32);   // halves hold partial sums over t
    if (split) {
        // unnormalized bf16 partial + (m, l); qp = qg - 1024 (qt >= 4)
        const int qp = qg - 1024;
        __bf16* prow = Opart + (((size_t)(half * 64 + bh) * 1024) + qp) * 64;
        #pragma unroll
        for (int db = 0; db < 2; ++db) {
            #pragma unroll
            for (int g = 0; g < 4; ++g) {
                int d0 = db * 32 + g * 8 + 4 * hi;
                bf16x4 o4;
                o4.x = (__bf16)oacc[db][g * 4 + 0];
                o4.y = (__bf16)oacc[db][g * 4 + 1];
                o4.z = (__bf16)oacc[db][g * 4 + 2];
                o4.w = (__bf16)oacc[db][g * 4 + 3];
                *reinterpret_cast<bf16x4*>(prow + d0) = o4;
            }
        }
        if (hi == 0)
            Ml[(size_t)(half * 64 + bh) * 1024 + qp] = make_float2(mrow, lsumt);
    } else {
        const int b = bh >> 4, h = bh & 15;
        float inv = 1.0f / lsumt;
        __bf16* orow = Oa + ((size_t)(b * SS + qg)) * EDIM + h * HD;
        #pragma unroll
        for (int db = 0; db < 2; ++db) {
            #pragma unroll
            for (int g = 0; g < 4; ++g) {
                int d0 = db * 32 + g * 8 + 4 * hi;
                bf16x4 o4;
                o4.x = (__bf16)(oacc[db][g * 4 + 0] * inv);
                o4.y = (__bf16)(oacc[db][g * 4 + 1] * inv);
                o4.z = (__bf16)(oacc[db][g * 4 + 2] * inv);
                o4.w = (__bf16)(oacc[db][g * 4 + 3] * inv);
                *reinterpret_cast<bf16x4*>(orow + d0) = o4;
            }
        }
    }
}

// ---------------- merge pass: combine split-KV partials for q >= 1024 ----------
__global__ __launch_bounds__(256) void merge_kernel(const __bf16* __restrict__ Opart,
                                                    const float2* __restrict__ Ml,
                                                    __bf16* __restrict__ Oa) {
    int t = blockIdx.x * 256 + threadIdx.x;   // 64 bh * 1024 qp * 8 d-octets
    int d8 = t & 7;
    int qp = (t >> 3) & 1023;
    int bh = t >> 13;
    size_t r0 = ((size_t)bh * 1024 + qp);
    size_t r1 = ((size_t)(64 + bh) * 1024 + qp);
    float2 ml0 = Ml[r0], ml1 = Ml[r1];
    float m = fmaxf(ml0.x, ml1.x);
    float a0 = exp2f(ml0.x - m), a1 = exp2f(ml1.x - m);
    float inv = 1.0f / (a0 * ml0.y + a1 * ml1.y);
    bf16x8 o0 = *reinterpret_cast<const bf16x8*>(Opart + r0 * 64 + d8 * 8);
    bf16x8 o1 = *reinterpret_cast<const bf16x8*>(Opart + r1 * 64 + d8 * 8);
    bf16x8 r;
    #pragma unroll
    for (int j = 0; j < 8; ++j)
        r[j] = (__bf16)((a0 * (float)o0[j] + a1 * (float)o1[j]) * inv);
    int b = bh >> 4, h = bh & 15, q = 1024 + qp;
    *reinterpret_cast<bf16x8*>(Oa + ((size_t)(b * SS + q)) * EDIM + h * HD + d8 * 8) = r;
}

// ---------------- launch ----------------
extern "C" void kernel_launch(void* const* d_in, const int* in_sizes, int n_in,
                              void* d_out, int out_size, void* d_ws, size_t ws_size,
                              hipStream_t stream) {
    const float* x  = (const float*)d_in[0];
    const float* Wq = (const float*)d_in[1];
    const float* bq = (const float*)d_in[2];
    const float* Wk = (const float*)d_in[3];
    const float* bk = (const float*)d_in[4];
    const float* Wv = (const float*)d_in[5];
    const float* bv = (const float*)d_in[6];
    const float* Wo = (const float*)d_in[7];
    const float* bo = (const float*)d_in[8];

    char* ws = (char*)d_ws;
    const size_t SZ_XB  = (size_t)MROWS * EDIM * 2;       // 16 MB
    const size_t SZ_W   = (size_t)EDIM * EDIM * 2;        // 2 MB
    const size_t SZ_QKV = (size_t)BB * NH * SS * HD * 2;  // 16 MB

    __bf16* xb  = (__bf16*)(ws);
    __bf16* wqb = (__bf16*)(ws + SZ_XB);                  // wq|wk|wv|wo contiguous
    __bf16* wob = (__bf16*)(ws + SZ_XB + 3 * SZ_W);
    __bf16* Qb  = (__bf16*)(ws + SZ_XB + 4 * SZ_W);
    __bf16* Kb  = (__bf16*)(ws + SZ_XB + 4 * SZ_W + SZ_QKV);
    __bf16* Vtb = (__bf16*)(ws + SZ_XB + 4 * SZ_W + 2 * SZ_QKV);
    __bf16* Oab = (__bf16*)(ws + SZ_XB + 4 * SZ_W + 3 * SZ_QKV);
    // split-KV scratch (reuses regions dead after gemm_qkv):
    __bf16* Opart = (__bf16*)(ws);                        // xb region, exactly 16 MB
    float2* Mlb   = (float2*)(ws + SZ_XB);                // wq region (dead), 1 MB

    cvt_kernel<<<MROWS * EDIM / 1024, 256, 0, stream>>>(x, xb, MROWS * EDIM);
    cvt4_kernel<<<4096, 256, 0, stream>>>(Wq, Wk, Wv, Wo, wqb);

    // fused QKV projection: N = 3072
    gemm_qkv<<<dim3(MROWS / 128, 3 * EDIM / 128), 256, 0, stream>>>(
        xb, wqb, bq, bk, bv, Qb, Kb, Vtb);

    attn_kernel<<<dim3(BB * NH, 12), 512, 0, stream>>>(Qb, Kb, Vtb, Oab, Opart, Mlb);
    merge_kernel<<<64 * 1024 * 8 / 256, 256, 0, stream>>>(Opart, Mlb, Oab);

    gemm_out<<<dim3(MROWS / 128, EDIM / 128), 256, 0, stream>>>(
        Oab, wob, bo, (float*)d_out);
}

// Round 29
// 175.411 us; speedup vs baseline: 1.1208x; 1.0047x over previous
//
#include <hip/hip_runtime.h>
#include <hip/hip_bf16.h>
#include <stdint.h>

// Problem constants
#define EDIM 1024
#define NH   16
#define HD   64
#define BB   4
#define SS   2048
#define MROWS (BB*SS)   // 8192

typedef __bf16 bf16x8 __attribute__((ext_vector_type(8)));
typedef __bf16 bf16x4 __attribute__((ext_vector_type(4)));
typedef float  f32x4  __attribute__((ext_vector_type(4)));
typedef float  f32x16 __attribute__((ext_vector_type(16)));
typedef int    int2v  __attribute__((ext_vector_type(2)));

__device__ __forceinline__ void async16(const void* g, void* lds) {
    __builtin_amdgcn_global_load_lds((__attribute__((address_space(1))) void*)(g),
                                     (__attribute__((address_space(3))) void*)(lds),
                                     16, 0, 0);
}

__device__ __forceinline__ f32x4 mfma16(bf16x8 a, bf16x8 b, f32x4 c) {
    return __builtin_amdgcn_mfma_f32_16x16x32_bf16(a, b, c, 0, 0, 0);
}
__device__ __forceinline__ f32x16 mfma32(bf16x8 a, bf16x8 b, f32x16 c) {
    return __builtin_amdgcn_mfma_f32_32x32x16_bf16(a, b, c, 0, 0, 0);
}

// pack two f32 -> one u32 of 2 bf16 (compiler emits v_cvt_pk_bf16_f32)
__device__ __forceinline__ int pkbf16(float a, float b) {
    union { __bf16 h[2]; int i; } u;
    u.h[0] = (__bf16)a; u.h[1] = (__bf16)b;
    return u.i;
}

// ---------------- fp32 -> bf16 conversion (vectorized) ----------------
__global__ __launch_bounds__(256) void cvt_kernel(const float* __restrict__ s,
                                                  __bf16* __restrict__ d, int n) {
    int i = (blockIdx.x * 256 + threadIdx.x) * 4;
    if (i < n) {
        float4 v = *reinterpret_cast<const float4*>(s + i);
        bf16x4 o;
        o.x = (__bf16)v.x; o.y = (__bf16)v.y; o.z = (__bf16)v.z; o.w = (__bf16)v.w;
        *reinterpret_cast<bf16x4*>(d + i) = o;
    }
}

// fused conversion of the 4 weight matrices (dest contiguous: wq|wk|wv|wo)
__global__ __launch_bounds__(256) void cvt4_kernel(const float* __restrict__ s0,
                                                   const float* __restrict__ s1,
                                                   const float* __restrict__ s2,
                                                   const float* __restrict__ s3,
                                                   __bf16* __restrict__ d) {
    int m = blockIdx.x >> 10;                     // 1024 blocks per matrix
    const float* s = (m == 0) ? s0 : (m == 1) ? s1 : (m == 2) ? s2 : s3;
    int i = ((blockIdx.x & 1023) * 256 + threadIdx.x) * 4;
    float4 v = *reinterpret_cast<const float4*>(s + i);
    bf16x4 o;
    o.x = (__bf16)v.x; o.y = (__bf16)v.y; o.z = (__bf16)v.z; o.w = (__bf16)v.w;
    *reinterpret_cast<bf16x4*>(d + (size_t)m * (EDIM * EDIM) + i) = o;
}

// ---- shared GEMM helpers: 128x128 tile, BK=64, dbuf, 8-slot XOR swizzle ----
// LDS tile: 128 rows x 128 B (64 bf16). Physical slot = logical_slot ^ (row&7).
struct GCtx { const __bf16 *ap, *bp; };

__device__ __forceinline__ void g_stage(GCtx& c, char* As, char* Bs, int wb) {
    #pragma unroll
    for (int i = 0; i < 4; ++i) {
        async16(c.ap + i * 32 * EDIM, As + wb + i * 4096);
        async16(c.bp + i * 32 * EDIM, Bs + wb + i * 4096);
    }
    c.ap += 64; c.bp += 64;
}

__device__ __forceinline__ void g_compute(const char* As, const char* Bs,
                                          int wm, int wn, int lrow, int lslot,
                                          f32x4 acc[4][4]) {
    #pragma unroll
    for (int kc = 0; kc < 2; ++kc) {
        bf16x8 af[4], bfr[4];
        #pragma unroll
        for (int mf = 0; mf < 4; ++mf) {
            int row = wm + mf * 16 + lrow;
            af[mf] = *reinterpret_cast<const bf16x8*>(
                As + row * 128 + (((kc * 4 + lslot) ^ (row & 7)) << 4));
        }
        #pragma unroll
        for (int nf = 0; nf < 4; ++nf) {
            int row = wn + nf * 16 + lrow;
            bfr[nf] = *reinterpret_cast<const bf16x8*>(
                Bs + row * 128 + (((kc * 4 + lslot) ^ (row & 7)) << 4));
        }
        __builtin_amdgcn_s_setprio(1);
        #pragma unroll
        for (int mf = 0; mf < 4; ++mf)
            #pragma unroll
            for (int nf = 0; nf < 4; ++nf)
                acc[mf][nf] = mfma16(af[mf], bfr[nf], acc[mf][nf]);
        __builtin_amdgcn_s_setprio(0);
    }
}

#define GEMM_DBUF_LOOP()                                                      \
    g_stage(ctx, As0, Bs0, wb);                                               \
    for (int kt = 0; kt < 16; kt += 2) {                                      \
        g_stage(ctx, As1, Bs1, wb);                                           \
        asm volatile("s_waitcnt vmcnt(8)" ::: "memory");                      \
        __builtin_amdgcn_s_barrier();                                         \
        __builtin_amdgcn_sched_barrier(0);                                    \
        g_compute(As0, Bs0, wm, wn, lrow, lslot, acc);                        \
        __builtin_amdgcn_sched_barrier(0);                                    \
        __builtin_amdgcn_s_barrier();                                         \
        if (kt + 2 < 16) {                                                    \
            g_stage(ctx, As0, Bs0, wb);                                       \
            asm volatile("s_waitcnt vmcnt(8)" ::: "memory");                  \
        } else {                                                              \
            asm volatile("s_waitcnt vmcnt(0)" ::: "memory");                  \
        }                                                                     \
        __builtin_amdgcn_s_barrier();                                         \
        __builtin_amdgcn_sched_barrier(0);                                    \
        g_compute(As1, Bs1, wm, wn, lrow, lslot, acc);                        \
        __builtin_amdgcn_sched_barrier(0);                                    \
        __builtin_amdgcn_s_barrier();                                         \
    }

// XCD-aware block remap (T1): neutral-measured (R26), kept as harmless.
#define GEMM_PREAMBLE(Aptr, Wptr)                                             \
    const int tid = threadIdx.x;                                              \
    const int w = tid >> 6, l = tid & 63;                                     \
    const int _b = blockIdx.y * 64 + blockIdx.x;                              \
    const int _g = _b & 7, _i = _b >> 3;                                      \
    const int bm = (_g * 8 + (_i & 7)) * 128, bn = (_i >> 3) * 128;           \
    const int wm = (w >> 1) * 64, wn = (w & 1) * 64;                          \
    f32x4 acc[4][4] = {};                                                     \
    const int lrow = l & 15;                                                  \
    const int lslot = l >> 4;                                                 \
    const int row0 = tid >> 3;                                                \
    const int gs = ((tid & 7) ^ (row0 & 7)) << 3;                             \
    const int wb = w * 1024;                                                  \
    GCtx ctx;                                                                 \
    ctx.ap = (Aptr) + (size_t)(bm + row0) * EDIM + gs;                        \
    ctx.bp = (Wptr) + (size_t)(bn + row0) * EDIM + gs;

// ---------------- Fused QKV GEMM: N=3072 (W rows 0..1023=Q, ..2047=K, ..3071=V) --
__global__ __launch_bounds__(256) void gemm_qkv(const __bf16* __restrict__ A,
                                                const __bf16* __restrict__ W,
                                                const float* __restrict__ bq,
                                                const float* __restrict__ bk,
                                                const float* __restrict__ bv,
                                                __bf16* __restrict__ Qb,
                                                __bf16* __restrict__ Kb,
                                                __bf16* __restrict__ Vtb) {
    __shared__ char As0[128 * 128], Bs0[128 * 128];
    __shared__ char As1[128 * 128], Bs1[128 * 128];
    GEMM_PREAMBLE(A, W)
    GEMM_DBUF_LOOP()

    const int mat = bn >> 10;                       // 0=Q, 1=K, 2=V (block-uniform)
    const float* bias = (mat == 0) ? bq : (mat == 1) ? bk : bv;

    if (mat == 2) {
        // V^T: packed bf16x4 along s (r=0..3 consecutive), coalesced-ish 8B stores
        #pragma unroll
        for (int nf = 0; nf < 4; ++nf) {
            int nn = (bn + wn + nf * 16 + lrow) & 1023;
            int h = nn >> 6, d = nn & 63;
            float bval = bias[nn];
            #pragma unroll
            for (int mf = 0; mf < 4; ++mf) {
                int mg0 = bm + wm + mf * 16 + (l >> 4) * 4;
                int b = mg0 >> 11, s = mg0 & 2047;
                bf16x4 o4;
                o4.x = (__bf16)(acc[mf][nf][0] + bval);
                o4.y = (__bf16)(acc[mf][nf][1] + bval);
                o4.z = (__bf16)(acc[mf][nf][2] + bval);
                o4.w = (__bf16)(acc[mf][nf][3] + bval);
                *reinterpret_cast<bf16x4*>(
                    Vtb + ((size_t)(b * NH + h) * HD + d) * SS + s) = o4;
            }
        }
    } else {
        __bf16* qk = (mat == 0) ? Qb : Kb;
        #pragma unroll
        for (int nf = 0; nf < 4; ++nf) {
            int nn = (bn + wn + nf * 16 + lrow) & 1023;
            int h = nn >> 6, d = nn & 63;
            float bval = bias[nn];
            #pragma unroll
            for (int mf = 0; mf < 4; ++mf) {
                #pragma unroll
                for (int r = 0; r < 4; ++r) {
                    int mg = bm + wm + mf * 16 + (l >> 4) * 4 + r;
                    int b = mg >> 11, s = mg & 2047;
                    qk[((size_t)(b * NH + h) * SS + s) * HD + d] =
                        (__bf16)(acc[mf][nf][r] + bval);
                }
            }
        }
    }
}

// ---------------- Output GEMM: fp32 out ----------------
__global__ __launch_bounds__(256) void gemm_out(const __bf16* __restrict__ A,
                                                const __bf16* __restrict__ W,
                                                const float* __restrict__ bias,
                                                float* __restrict__ dst) {
    __shared__ char As0[128 * 128], Bs0[128 * 128];
    __shared__ char As1[128 * 128], Bs1[128 * 128];
    GEMM_PREAMBLE(A, W)
    GEMM_DBUF_LOOP()

    #pragma unroll
    for (int nf = 0; nf < 4; ++nf) {
        int ng = bn + wn + nf * 16 + lrow;
        float bval = bias[ng];
        #pragma unroll
        for (int mf = 0; mf < 4; ++mf) {
            #pragma unroll
            for (int r = 0; r < 4; ++r) {
                int mg = bm + wm + mf * 16 + (l >> 4) * 4 + r;
                dst[(size_t)mg * EDIM + ng] = acc[mf][nf][r] + bval;
            }
        }
    }
}

// ---------------- Flash attention pass 1 (causal, swapped-QK^T, split-KV) ----
// blockIdx.y decode: y<8 -> SPLIT qt = 7-(y>>1), half = y&1 (qt 4..7);
//                    y>=8 -> UNSPLIT qt = 11-y (qt 3..0).
#define SCL2E 0.18033688f   /* 0.125 * log2(e) */

__global__ __launch_bounds__(512) void attn_kernel(const __bf16* __restrict__ Q,
                                                   const __bf16* __restrict__ K,
                                                   const __bf16* __restrict__ Vt,
                                                   __bf16* __restrict__ Oa,
                                                   __bf16* __restrict__ Opart,
                                                   float2* __restrict__ Ml) {
    __shared__ char ks0[64 * 128], vs0[64 * 128];
    __shared__ char ks1[64 * 128], vs1[64 * 128];

    const int bh = blockIdx.x;          // 0..63
    const int y = blockIdx.y;           // 0..11
    const bool split = (y < 8);
    const int qt = split ? (7 - (y >> 1)) : (11 - y);
    const int half = split ? (y & 1) : 0;
    const int tid = threadIdx.x;
    const int w = tid >> 6;             // warp 0..7
    const int l = tid & 63;
    const int lo = l & 31;
    const int hi = l >> 5;

    const __bf16* Qp = Q + (size_t)bh * (SS * HD);
    const __bf16* Kp = K + (size_t)bh * (SS * HD);
    const __bf16* Vp = Vt + (size_t)bh * (HD * SS);

    // Q B-fragments: col=q=lo, k = d = kc*16 + hi*8 + j
    const int qg = qt * 256 + w * 32 + lo;
    bf16x8 qf[4];
    #pragma unroll
    for (int kc = 0; kc < 4; ++kc)
        qf[kc] = *reinterpret_cast<const bf16x8*>(Qp + (size_t)qg * HD + kc * 16 + hi * 8);

    // KV tile range for this block
    const int nt_all = 4 * qt + 4;
    const int tcount = split ? (nt_all >> 1) : nt_all;    // always even
    const int kt0 = split ? (half * tcount) : 0;

    // staging: one 16B chunk per thread per matrix
    const int rowS = tid >> 3, cbS = tid & 7;
    const int gsS = (cbS ^ (rowS & 7)) << 3;
    const int wb = w * 1024;
    const __bf16* kp = Kp + (size_t)(kt0 * 64 + rowS) * HD + gsS;
    const __bf16* vp = Vp + (size_t)rowS * SS + kt0 * 64 + gsS;

    f32x16 oacc[2] = {};                 // O^T[d][q = lo]
    float mrow = -1e30f;
    float lsum = 0.f;

    const int qwhi = qt * 256 + w * 32 + 31;

    auto compute = [&](const char* ksb, const char* vsb, int kv0) {
        f32x16 acc[2] = {};
        __builtin_amdgcn_s_setprio(1);
        #pragma unroll
        for (int tb = 0; tb < 2; ++tb) {
            const int t = tb * 32 + lo;
            const char* krow = ksb + t * 128;
            const int tx = (t & 7);
            #pragma unroll
            for (int kc = 0; kc < 4; ++kc) {
                bf16x8 kf = *reinterpret_cast<const bf16x8*>(krow + ((2 * kc + hi) ^ tx) * 16);
                acc[tb] = mfma32(kf, qf[kc], acc[tb]);
            }
        }
        __builtin_amdgcn_s_setprio(0);

        // causal mask near the diagonal (warp-uniform predicate)
        if (kv0 + 63 > qg - lo) {
            #pragma unroll
            for (int tb = 0; tb < 2; ++tb)
                #pragma unroll
                for (int r = 0; r < 16; ++r) {
                    int t = kv0 + tb * 32 + ((r & 3) + 8 * (r >> 2)) + 4 * hi;
                    if (t > qg) acc[tb][r] = -1e30f;
                }
        }

        // in-register online softmax (scalar m/lsum per lane; row = q = lo)
        float mx = acc[0][0];
        #pragma unroll
        for (int r = 1; r < 16; ++r) mx = fmaxf(mx, acc[0][r]);
        #pragma unroll
        for (int r = 0; r < 16; ++r) mx = fmaxf(mx, acc[1][r]);
        mx = fmaxf(mx, __shfl_xor(mx, 32));
        float mxs = mx * SCL2E;
        if (!__all(mxs <= mrow + 8.0f)) {        // T13 defer-max
            float mnew = fmaxf(mrow, mxs);
            float alpha = exp2f(mrow - mnew);
            mrow = mnew;
            lsum *= alpha;
            oacc[0] *= alpha;
            oacc[1] *= alpha;
        }
        float psum = 0.f;
        #pragma unroll
        for (int tb = 0; tb < 2; ++tb)
            #pragma unroll
            for (int r = 0; r < 16; ++r) {
                float p = exp2f(fmaf(acc[tb][r], SCL2E, -mrow));
                acc[tb][r] = p;
                psum += p;
            }
        lsum += psum;

        // P -> bf16 fragments via cvt_pk + permlane32_swap
        bf16x8 pa[4];
        #pragma unroll
        for (int ks2 = 0; ks2 < 4; ++ks2) {
            const int tb = ks2 >> 1, rb = (ks2 & 1) * 8;
            int a0 = pkbf16(acc[tb][rb + 0], acc[tb][rb + 1]);
            int b0 = pkbf16(acc[tb][rb + 4], acc[tb][rb + 5]);
            int a1 = pkbf16(acc[tb][rb + 2], acc[tb][rb + 3]);
            int b1 = pkbf16(acc[tb][rb + 6], acc[tb][rb + 7]);
            int2v s1 = __builtin_amdgcn_permlane32_swap(a0, b0, false, false);
            int2v s2 = __builtin_amdgcn_permlane32_swap(a1, b1, false, false);
            union { int i[4]; bf16x8 v; } u;
            u.i[0] = s1[0]; u.i[1] = s2[0]; u.i[2] = s1[1]; u.i[3] = s2[1];
            pa[ks2] = u.v;
        }

        // PV transposed: O^T[d][q] += V^T[d][t] * P^T[t][q]
        __builtin_amdgcn_s_setprio(1);
        #pragma unroll
        for (int ks2 = 0; ks2 < 4; ++ks2) {
            #pragma unroll
            for (int db = 0; db < 2; ++db) {
                const int d = db * 32 + lo;
                bf16x8 vb = *reinterpret_cast<const bf16x8*>(
                    vsb + d * 128 + (((2 * ks2 + hi) ^ (d & 7)) * 16));
                oacc[db] = mfma32(vb, pa[ks2], oacc[db]);
            }
        }
        __builtin_amdgcn_s_setprio(0);
    };

    // prologue: stage tile 0 into buffer 0
    async16(kp, ks0 + wb);
    async16(vp, vs0 + wb);
    kp += 64 * HD; vp += 64;

    for (int kt = 0; kt < tcount; kt += 2) {
        // ---- phase A: compute tile kt (buf0); prefetch kt+1 -> buf1
        async16(kp, ks1 + wb);
        async16(vp, vs1 + wb);
        kp += 64 * HD; vp += 64;
        asm volatile("s_waitcnt vmcnt(2)" ::: "memory");   // tile kt landed
        __builtin_amdgcn_s_barrier();
        __builtin_amdgcn_sched_barrier(0);
        if ((kt0 + kt) * 64 <= qwhi) compute(ks0, vs0, (kt0 + kt) * 64);
        __builtin_amdgcn_sched_barrier(0);
        __builtin_amdgcn_s_barrier();                      // buf0 reads done

        // ---- phase B: compute tile kt+1 (buf1); prefetch kt+2 -> buf0
        if (kt + 2 < tcount) {
            async16(kp, ks0 + wb);
            async16(vp, vs0 + wb);
            kp += 64 * HD; vp += 64;
            asm volatile("s_waitcnt vmcnt(2)" ::: "memory");
        } else {
            asm volatile("s_waitcnt vmcnt(0)" ::: "memory");
        }
        __builtin_amdgcn_s_barrier();
        __builtin_amdgcn_sched_barrier(0);
        if ((kt0 + kt + 1) * 64 <= qwhi) compute(ks1, vs1, (kt0 + kt + 1) * 64);
        __builtin_amdgcn_sched_barrier(0);
        __builtin_amdgcn_s_barrier();                      // buf1 reads done
    }

    // epilogue
    float lsumt = lsum + __shfl_xor(lsum, 32);   // halves hold partial sums over t
    if (split) {
        // unnormalized bf16 partial + (m, l); qp = qg - 1024 (qt >= 4)
        const int qp = qg - 1024;
        __bf16* prow = Opart + (((size_t)(half * 64 + bh) * 1024) + qp) * 64;
        #pragma unroll
        for (int db = 0; db < 2; ++db) {
            #pragma unroll
            for (int g = 0; g < 4; ++g) {
                int d0 = db * 32 + g * 8 + 4 * hi;
                bf16x4 o4;
                o4.x = (__bf16)oacc[db][g * 4 + 0];
                o4.y = (__bf16)oacc[db][g * 4 + 1];
                o4.z = (__bf16)oacc[db][g * 4 + 2];
                o4.w = (__bf16)oacc[db][g * 4 + 3];
                *reinterpret_cast<bf16x4*>(prow + d0) = o4;
            }
        }
        if (hi == 0)
            Ml[(size_t)(half * 64 + bh) * 1024 + qp] = make_float2(mrow, lsumt);
    } else {
        const int b = bh >> 4, h = bh & 15;
        float inv = 1.0f / lsumt;
        __bf16* orow = Oa + ((size_t)(b * SS + qg)) * EDIM + h * HD;
        #pragma unroll
        for (int db = 0; db < 2; ++db) {
            #pragma unroll
            for (int g = 0; g < 4; ++g) {
                int d0 = db * 32 + g * 8 + 4 * hi;
                bf16x4 o4;
                o4.x = (__bf16)(oacc[db][g * 4 + 0] * inv);
                o4.y = (__bf16)(oacc[db][g * 4 + 1] * inv);
                o4.z = (__bf16)(oacc[db][g * 4 + 2] * inv);
                o4.w = (__bf16)(oacc[db][g * 4 + 3] * inv);
                *reinterpret_cast<bf16x4*>(orow + d0) = o4;
            }
        }
    }
}

// ---------------- merge pass: combine split-KV partials for q >= 1024 ----------
__global__ __launch_bounds__(256) void merge_kernel(const __bf16* __restrict__ Opart,
                                                    const float2* __restrict__ Ml,
                                                    __bf16* __restrict__ Oa) {
    int t = blockIdx.x * 256 + threadIdx.x;   // 64 bh * 1024 qp * 8 d-octets
    int d8 = t & 7;
    int qp = (t >> 3) & 1023;
    int bh = t >> 13;
    size_t r0 = ((size_t)bh * 1024 + qp);
    size_t r1 = ((size_t)(64 + bh) * 1024 + qp);
    float2 ml0 = Ml[r0], ml1 = Ml[r1];
    float m = fmaxf(ml0.x, ml1.x);
    float a0 = exp2f(ml0.x - m), a1 = exp2f(ml1.x - m);
    float inv = 1.0f / (a0 * ml0.y + a1 * ml1.y);
    bf16x8 o0 = *reinterpret_cast<const bf16x8*>(Opart + r0 * 64 + d8 * 8);
    bf16x8 o1 = *reinterpret_cast<const bf16x8*>(Opart + r1 * 64 + d8 * 8);
    bf16x8 r;
    #pragma unroll
    for (int j = 0; j < 8; ++j)
        r[j] = (__bf16)((a0 * (float)o0[j] + a1 * (float)o1[j]) * inv);
    int b = bh >> 4, h = bh & 15, q = 1024 + qp;
    *reinterpret_cast<bf16x8*>(Oa + ((size_t)(b * SS + q)) * EDIM + h * HD + d8 * 8) = r;
}

// ---------------- launch ----------------
extern "C" void kernel_launch(void* const* d_in, const int* in_sizes, int n_in,
                              void* d_out, int out_size, void* d_ws, size_t ws_size,
                              hipStream_t stream) {
    const float* x  = (const float*)d_in[0];
    const float* Wq = (const float*)d_in[1];
    const float* bq = (const float*)d_in[2];
    const float* Wk = (const float*)d_in[3];
    const float* bk = (const float*)d_in[4];
    const float* Wv = (const float*)d_in[5];
    const float* bv = (const float*)d_in[6];
    const float* Wo = (const float*)d_in[7];
    const float* bo = (const float*)d_in[8];

    char* ws = (char*)d_ws;
    const size_t SZ_XB  = (size_t)MROWS * EDIM * 2;       // 16 MB
    const size_t SZ_W   = (size_t)EDIM * EDIM * 2;        // 2 MB
    const size_t SZ_QKV = (size_t)BB * NH * SS * HD * 2;  // 16 MB

    __bf16* xb  = (__bf16*)(ws);
    __bf16* wqb = (__bf16*)(ws + SZ_XB);                  // wq|wk|wv|wo contiguous
    __bf16* wob = (__bf16*)(ws + SZ_XB + 3 * SZ_W);
    __bf16* Qb  = (__bf16*)(ws + SZ_XB + 4 * SZ_W);
    __bf16* Kb  = (__bf16*)(ws + SZ_XB + 4 * SZ_W + SZ_QKV);
    __bf16* Vtb = (__bf16*)(ws + SZ_XB + 4 * SZ_W + 2 * SZ_QKV);
    __bf16* Oab = (__bf16*)(ws + SZ_XB + 4 * SZ_W + 3 * SZ_QKV);
    // split-KV scratch (reuses regions dead after gemm_qkv):
    __bf16* Opart = (__bf16*)(ws);                        // xb region, exactly 16 MB
    float2* Mlb   = (float2*)(ws + SZ_XB);                // wq region (dead), 1 MB

    cvt_kernel<<<MROWS * EDIM / 1024, 256, 0, stream>>>(x, xb, MROWS * EDIM);
    cvt4_kernel<<<4096, 256, 0, stream>>>(Wq, Wk, Wv, Wo, wqb);

    // fused QKV projection: N = 3072
    gemm_qkv<<<dim3(MROWS / 128, 3 * EDIM / 128), 256, 0, stream>>>(
        xb, wqb, bq, bk, bv, Qb, Kb, Vtb);

    attn_kernel<<<dim3(BB * NH, 12), 512, 0, stream>>>(Qb, Kb, Vtb, Oab, Opart, Mlb);
    merge_kernel<<<64 * 1024 * 8 / 256, 256, 0, stream>>>(Opart, Mlb, Oab);

    gemm_out<<<dim3(MROWS / 128, EDIM / 128), 256, 0, stream>>>(
        Oab, wob, bo, (float*)d_out);
}